// Round 2
// baseline (1176.031 us; speedup 1.0000x reference)
//
#include <hip/hip_runtime.h>

#define CDIM    256
#define KCODES  1024
#define HWSZ    4096            // 64*64
#define NROWS   131072          // 32*64*64
#define BM      64              // rows per block
#define BN      128             // codes per tile
#define CCH     64              // C chunk
#define XS_STR  68              // 64 + 4 pad
#define ES_STR  132             // 128 + 4 pad

// ---------- kernel 0a: A[n] = np.sum(x_row^2) with numpy pairwise tree (fp32) ----------
// numpy pairwise_sum, n=256: split 128+128; each 128-block: r[0..7]=a[0..7],
// r[j]+=a[i+j] for i=8..120, combine ((r0+r1)+(r2+r3))+((r4+r5)+(r6+r7)); sum halves.
// fp contract off: square rounds, then add rounds (matches np temp xf*xf then sum).
__global__ void rowsq_kernel(const float* __restrict__ x, float* __restrict__ A) {
#pragma clang fp contract(off)
    int n = blockIdx.x * 256 + threadIdx.x;           // grid covers all rows
    const float* xr = x + (size_t)(n >> 12) * (CDIM * HWSZ) + (n & 4095);
    float half_s[2];
    for (int h = 0; h < 2; ++h) {
        float r[8];
        #pragma unroll
        for (int j = 0; j < 8; ++j) {
            float v = xr[(size_t)(h * 128 + j) * HWSZ];
            r[j] = v * v;
        }
        for (int i = 8; i < 128; i += 8) {
            #pragma unroll
            for (int j = 0; j < 8; ++j) {
                float v = xr[(size_t)(h * 128 + i + j) * HWSZ];
                float sq = v * v;
                r[j] = r[j] + sq;
            }
        }
        half_s[h] = ((r[0] + r[1]) + (r[2] + r[3])) + ((r[4] + r[5]) + (r[6] + r[7]));
    }
    A[n] = half_s[0] + half_s[1];
}

// ---------- kernel 0b: B[k] = np.sum(cb_row^2), same numpy tree ----------
__global__ void codesq_kernel(const float* __restrict__ cb, float* __restrict__ Bq) {
#pragma clang fp contract(off)
    int k = blockIdx.x * 256 + threadIdx.x;
    if (k >= KCODES) return;
    const float* er = cb + (size_t)k * CDIM;
    float half_s[2];
    for (int h = 0; h < 2; ++h) {
        float r[8];
        #pragma unroll
        for (int j = 0; j < 8; ++j) {
            float v = er[h * 128 + j];
            r[j] = v * v;
        }
        for (int i = 8; i < 128; i += 8) {
            #pragma unroll
            for (int j = 0; j < 8; ++j) {
                float v = er[h * 128 + i + j];
                float sq = v * v;
                r[j] = r[j] + sq;
            }
        }
        half_s[h] = ((r[0] + r[1]) + (r[2] + r[3])) + ((r[4] + r[5]) + (r[6] + r[7]));
    }
    Bq[k] = half_s[0] + half_s[1];
}

// ---------- kernel 1: fused fp32 score + argmin, numpy-semantics ----------
// dist_k = fl32( fl32(A + B_k) - 2*M_k ), M_k = fp32 fmaf chain over c ascending
// (mirrors BLAS sgemm single-accumulator k-sequential reduction).
__global__ __launch_bounds__(256, 3)
void argmin_kernel(const float* __restrict__ x, const float* __restrict__ cb,
                   const float* __restrict__ A, const float* __restrict__ Bq,
                   int* __restrict__ idx_out, float* __restrict__ outF) {
    __shared__ float Xs[CCH * XS_STR];   // [c][row]
    __shared__ float Es[CCH * ES_STR];   // [c][code]

    const int t  = threadIdx.x;
    const int tx = t & 15;               // codes tx*8 .. tx*8+7
    const int ty = t >> 4;               // rows  ty*4 .. ty*4+3
    const int r0 = blockIdx.x * BM;
    const float* xbase = x + (size_t)(r0 >> 12) * (CDIM * HWSZ) + (r0 & 4095);

    float a4[4];
    #pragma unroll
    for (int i = 0; i < 4; ++i) a4[i] = A[r0 + ty * 4 + i];

    float bestS[4]; int bestI[4];
    #pragma unroll
    for (int i = 0; i < 4; ++i) { bestS[i] = 3.4e38f; bestI[i] = 0; }

    for (int kt = 0; kt < KCODES; kt += BN) {
        float acc[4][8];                 // fp32 dot accumulators, carried across all c
        #pragma unroll
        for (int i = 0; i < 4; ++i)
            #pragma unroll
            for (int j = 0; j < 8; ++j) acc[i][j] = 0.f;

        for (int c0 = 0; c0 < CDIM; c0 += CCH) {
            __syncthreads();
            // stage X: c-major, rows contiguous
            {
                int cc = t >> 4;
                int r4 = (t & 15) * 4;
                #pragma unroll
                for (int it = 0; it < 4; ++it, cc += 16) {
                    *(float4*)&Xs[cc * XS_STR + r4] =
                        *(const float4*)(xbase + (size_t)(c0 + cc) * HWSZ + r4);
                }
            }
            // stage E transposed: Es[c][k]
            {
                int k    = t >> 1;
                int half = t & 1;
                const float* erow = cb + (size_t)(kt + k) * CDIM + c0 + half * 32;
                #pragma unroll
                for (int jj = 0; jj < 8; ++jj) {
                    float4 v = *(const float4*)(erow + jj * 4);
                    int cc = half * 32 + jj * 4;
                    Es[(cc + 0) * ES_STR + k] = v.x;
                    Es[(cc + 1) * ES_STR + k] = v.y;
                    Es[(cc + 2) * ES_STR + k] = v.z;
                    Es[(cc + 3) * ES_STR + k] = v.w;
                }
            }
            __syncthreads();

            // c ascending: keeps the fmaf chain in BLAS order across chunks
            #pragma unroll 4
            for (int c = 0; c < CCH; ++c) {
                float4 xv = *(const float4*)&Xs[c * XS_STR + ty * 4];
                float4 ea = *(const float4*)&Es[c * ES_STR + tx * 8];
                float4 eb = *(const float4*)&Es[c * ES_STR + tx * 8 + 4];
                float xr[4] = {xv.x, xv.y, xv.z, xv.w};
                float ee[8] = {ea.x, ea.y, ea.z, ea.w, eb.x, eb.y, eb.z, eb.w};
                #pragma unroll
                for (int i = 0; i < 4; ++i)
                    #pragma unroll
                    for (int j = 0; j < 8; ++j)
                        acc[i][j] = fmaf(xr[i], ee[j], acc[i][j]);
            }
        }

        // fp32 score + per-row argmin over this 128-code tile
        float bq[8];
        #pragma unroll
        for (int j = 0; j < 8; ++j) bq[j] = Bq[kt + tx * 8 + j];
        #pragma unroll
        for (int i = 0; i < 4; ++i) {
            float bs = 3.4e38f; int bk = 0;
            #pragma unroll
            for (int j = 0; j < 8; ++j) {
                float T1 = a4[i] + bq[j];            // fl32(A + B_k)
                float s  = T1 - 2.0f * acc[i][j];    // fl32(T1 - 2M) (2M exact)
                int kk = kt + tx * 8 + j;
                if (s < bs) { bs = s; bk = kk; }     // ascending k: keeps lowest idx
            }
            #pragma unroll
            for (int m = 1; m < 16; m <<= 1) {
                float os = __shfl_xor(bs, m, 64);
                int   ok = __shfl_xor(bk, m, 64);
                if (os < bs || (os == bs && ok < bk)) { bs = os; bk = ok; }
            }
            if (bs < bestS[i] || (bs == bestS[i] && bk < bestI[i])) {
                bestS[i] = bs; bestI[i] = bk;
            }
        }
    }

    if (tx == 0) {
        #pragma unroll
        for (int i = 0; i < 4; ++i) {
            int r = r0 + ty * 4 + i;
            idx_out[r] = bestI[i];
            outF[r]    = (float)bestI[i];
        }
    }
}

// ---------- kernel 2: gather codebook rows + NHWC->NCHW transpose ----------
__global__ __launch_bounds__(256)
void gather_kernel(const float* __restrict__ cb, const int* __restrict__ idx,
                   float* __restrict__ out) {
    __shared__ int   sIdx[64];
    __shared__ float tile[64 * 129];
    const int t  = threadIdx.x;
    const int bh = blockIdx.x;
    const int b  = bh >> 6, h = bh & 63;

    if (t < 64) {
        int id = idx[bh * 64 + t];
        sIdx[t] = id;
        out[bh * 64 + t] = (float)id;
    }
    __syncthreads();

    float* qout = out + NROWS + (size_t)b * (CDIM * HWSZ) + h * 64;

    for (int c0 = 0; c0 < CDIM; c0 += 128) {
        if (c0) __syncthreads();
        {
            int w = t >> 2, seg = t & 3;
            const float* crow = cb + (size_t)sIdx[w] * CDIM + c0;
            #pragma unroll
            for (int jj = 0; jj < 8; ++jj) {
                int f = seg + 4 * jj;
                float4 v = *(const float4*)(crow + 4 * f);
                float* dst = &tile[w * 129 + 4 * f];
                dst[0] = v.x; dst[1] = v.y; dst[2] = v.z; dst[3] = v.w;
            }
        }
        __syncthreads();
        {
            int g = t >> 4, w4 = (t & 15) * 4;
            #pragma unroll
            for (int it = 0; it < 8; ++it) {
                int cl = it * 16 + g;
                float4 v;
                v.x = tile[(w4 + 0) * 129 + cl];
                v.y = tile[(w4 + 1) * 129 + cl];
                v.z = tile[(w4 + 2) * 129 + cl];
                v.w = tile[(w4 + 3) * 129 + cl];
                *(float4*)(qout + (size_t)(c0 + cl) * HWSZ + w4) = v;
            }
        }
    }
}

extern "C" void kernel_launch(void* const* d_in, const int* in_sizes, int n_in,
                              void* d_out, int out_size, void* d_ws, size_t ws_size,
                              hipStream_t stream) {
    const float* x  = (const float*)d_in[0];
    const float* cb = (const float*)d_in[1];
    float* A     = (float*)d_ws;                           // 512 KB
    float* Bq    = (float*)((char*)d_ws + 524288);         // 4 KB
    int*   idxbf = (int*)((char*)d_ws + 528384);           // 512 KB
    float* out   = (float*)d_out;

    rowsq_kernel<<<NROWS / 256, 256, 0, stream>>>(x, A);
    codesq_kernel<<<KCODES / 256, 256, 0, stream>>>(cb, Bq);
    argmin_kernel<<<NROWS / BM, 256, 0, stream>>>(x, cb, A, Bq, idxbf, out);
    gather_kernel<<<32 * 64, 256, 0, stream>>>(cb, idxbf, out);
}